// Round 1
// baseline (2953.857 us; speedup 1.0000x reference)
//
#include <hip/hip_runtime.h>
#include <cstddef>

typedef _Float16 half8   __attribute__((ext_vector_type(8)));
typedef _Float16 half4_t __attribute__((ext_vector_type(4)));
typedef float    float4_t __attribute__((ext_vector_type(4)));

#define T_STEPS 128
#define BATCH   2048
#define DATA    64
#define DIM     128
#define WIDTH   256
#define SUBSTEPS 4
#define BT      16            // batch tile per workgroup (= MFMA N)
#define NWG     (BATCH / BT)  // 128 workgroups
#define NTHREADS 512          // 8 waves
#define SPY (DIM + 8)         // 136 halfs -> 272 B row stride (16B multiple)
#define SPH (WIDTH + 8)       // 264 halfs -> 528 B row stride (16B multiple)

#define MFMA16(A, B, C) __builtin_amdgcn_mfma_f32_16x16x32_f16((A), (B), (C), 0, 0, 0)

__global__ __launch_bounds__(NTHREADS, 2)
void anode_kernel(const float* __restrict__ ts, const float* __restrict__ y0,
                  const float* __restrict__ W1, const float* __restrict__ b1,
                  const float* __restrict__ W2, const float* __restrict__ b2,
                  const float* __restrict__ W3, const float* __restrict__ b3,
                  float* __restrict__ out)
{
  // Activation ping-pong buffers, [n][k] layout, padded for bank spread.
  __shared__ __align__(16) _Float16 Yb[BT * SPY];
  __shared__ __align__(16) _Float16 H1[BT * SPH];
  __shared__ __align__(16) _Float16 H2[BT * SPH];

  const int tid  = threadIdx.x;
  const int wave = tid >> 6;
  const int lane = tid & 63;
  const int n    = lane & 15;   // batch column within tile (MFMA N index)
  const int quad = lane >> 4;   // 0..3
  const int bbase = blockIdx.x * BT;

  // Load 8 consecutive fp32, convert to a fp16 MFMA fragment register.
  auto ld8 = [](const float* p) -> half8 {
    float4_t u0 = *(const float4_t*)p;
    float4_t u1 = *(const float4_t*)(p + 4);
    half8 r;
    r[0]=(_Float16)u0[0]; r[1]=(_Float16)u0[1]; r[2]=(_Float16)u0[2]; r[3]=(_Float16)u0[3];
    r[4]=(_Float16)u1[0]; r[5]=(_Float16)u1[1]; r[6]=(_Float16)u1[2]; r[7]=(_Float16)u1[3];
    return r;
  };

  // ---- Weights resident in VGPRs as MFMA A-fragments ----
  // A-layout (16x16x32): lane holds A[m = Mbase + (lane&15)][k = kt*32 + quad*8 + j]
  // wave w owns M rows [32w,32w+32) for W1/W2 (2 M-tiles), [16w,16w+16) for W3.
  half8 a1[2][4];   // W1: 256x128
  half8 a2[2][8];   // W2: 256x256
  half8 a3[8];      // W3: 128x256
  float4_t bv1[2], bv2[2], bv3;  // bias per acc reg: b[Mbase + quad*4 + r]

  #pragma unroll
  for (int mt = 0; mt < 2; ++mt) {
    const int m = wave * 32 + mt * 16 + n;
    #pragma unroll
    for (int kt = 0; kt < 4; ++kt)
      a1[mt][kt] = ld8(W1 + (size_t)m * DIM + kt * 32 + quad * 8);
    #pragma unroll
    for (int kt = 0; kt < 8; ++kt)
      a2[mt][kt] = ld8(W2 + (size_t)m * WIDTH + kt * 32 + quad * 8);
    bv1[mt] = *(const float4_t*)(b1 + wave * 32 + mt * 16 + quad * 4);
    bv2[mt] = *(const float4_t*)(b2 + wave * 32 + mt * 16 + quad * 4);
  }
  {
    const int m3 = wave * 16 + n;
    #pragma unroll
    for (int kt = 0; kt < 8; ++kt)
      a3[kt] = ld8(W3 + (size_t)m3 * WIDTH + kt * 32 + quad * 8);
    bv3 = *(const float4_t*)(b3 + wave * 16 + quad * 4);
  }

  // Per-lane LDS pointers (kt*32 halfs added as immediate offsets).
  const _Float16* rdY  = Yb + n * SPY + quad * 8;
  const _Float16* rdH1 = H1 + n * SPH + quad * 8;
  const _Float16* rdH2 = H2 + n * SPH + quad * 8;
  _Float16* wrY  = Yb + n * SPY + wave * 16 + quad * 4;
  _Float16* wrHa = H1 + n * SPH + wave * 32 + quad * 4;      // mt=0
  _Float16* wrHb = H1 + n * SPH + wave * 32 + 16 + quad * 4; // mt=1
  _Float16* wrGa = H2 + n * SPH + wave * 32 + quad * 4;
  _Float16* wrGb = H2 + n * SPH + wave * 32 + 16 + quad * 4;

  auto st4h = [](_Float16* p, float4_t v) {
    half4_t h;
    h[0]=(_Float16)v[0]; h[1]=(_Float16)v[1]; h[2]=(_Float16)v[2]; h[3]=(_Float16)v[3];
    *(half4_t*)p = h;
  };
  auto relu4 = [](float4_t v) -> float4_t {
    v[0]=fmaxf(v[0],0.f); v[1]=fmaxf(v[1],0.f); v[2]=fmaxf(v[2],0.f); v[3]=fmaxf(v[3],0.f);
    return v;
  };

  // f(y): depth-2 MLP. Stage arg enters/exits in MFMA C/D register layout:
  // lane owns dims d = wave*16 + quad*4 + r (r=0..3), batch col n.
  auto feval = [&](float4_t yin) -> float4_t {
    st4h(wrY, yin);
    __syncthreads();

    // layer 1: 256x128 @ 128x16
    float4_t c0 = bv1[0], c1 = bv1[1];
    #pragma unroll
    for (int kt = 0; kt < 4; ++kt) {
      half8 bk = *(const half8*)(rdY + kt * 32);
      c0 = MFMA16(a1[0][kt], bk, c0);
      c1 = MFMA16(a1[1][kt], bk, c1);
    }
    st4h(wrHa, relu4(c0));
    st4h(wrHb, relu4(c1));
    __syncthreads();

    // layer 2: 256x256 @ 256x16
    float4_t d0 = bv2[0], d1 = bv2[1];
    #pragma unroll
    for (int kt = 0; kt < 8; ++kt) {
      half8 bk = *(const half8*)(rdH1 + kt * 32);
      d0 = MFMA16(a2[0][kt], bk, d0);
      d1 = MFMA16(a2[1][kt], bk, d1);
    }
    st4h(wrGa, relu4(d0));
    st4h(wrGb, relu4(d1));
    __syncthreads();

    // layer 3: 128x256 @ 256x16 (linear)
    float4_t e0 = bv3;
    #pragma unroll
    for (int kt = 0; kt < 8; ++kt) {
      half8 bk = *(const half8*)(rdH2 + kt * 32);
      e0 = MFMA16(a3[kt], bk, e0);
    }
    return e0;
  };

  // ---- state init: y layout matches f-output layout ----
  float4_t y = *(const float4_t*)(y0 + (size_t)(bbase + n) * DIM + wave * 16 + quad * 4);

  // ys[0] = y0 (first 64 dims only -> waves 0..3)
  if (wave < 4)
    *(float4_t*)(out + (size_t)(bbase + n) * DATA + wave * 16 + quad * 4) = y;
  if (blockIdx.x == 0 && tid == 0)
    out[(size_t)T_STEPS * BATCH * DATA] = (float)((T_STEPS - 1) * SUBSTEPS); // 508.0f

  // Dopri5 coefficients
  const float A31=(float)(3.0/40.0),      A32=(float)(9.0/40.0);
  const float A41=(float)(44.0/45.0),     A42=(float)(-56.0/15.0),    A43=(float)(32.0/9.0);
  const float A51=(float)(19372.0/6561.0),A52=(float)(-25360.0/2187.0),
              A53=(float)(64448.0/6561.0),A54=(float)(-212.0/729.0);
  const float A61=(float)(9017.0/3168.0), A62=(float)(-355.0/33.0),
              A63=(float)(46732.0/5247.0),A64=(float)(49.0/176.0),    A65=(float)(-5103.0/18656.0);
  const float B1=(float)(35.0/384.0),     B3=(float)(500.0/1113.0),   B4=(float)(125.0/192.0),
              B5=(float)(-2187.0/6784.0), B6=(float)(11.0/84.0);

  for (int t = 0; t < T_STEPS - 1; ++t) {
    const float dt = (ts[t + 1] - ts[t]) * (1.0f / SUBSTEPS);
    for (int s = 0; s < SUBSTEPS; ++s) {
      float4_t k1 = feval(y);
      float4_t k2 = feval(y + (dt * 0.2f) * k1);
      float4_t k3 = feval(y + dt * (A31 * k1 + A32 * k2));
      float4_t k4 = feval(y + dt * (A41 * k1 + A42 * k2 + A43 * k3));
      float4_t k5 = feval(y + dt * (A51 * k1 + A52 * k2 + A53 * k3 + A54 * k4));
      float4_t k6 = feval(y + dt * (A61 * k1 + A62 * k2 + A63 * k3 + A64 * k4 + A65 * k5));
      y = y + dt * (B1 * k1 + B3 * k3 + B4 * k4 + B5 * k5 + B6 * k6);
    }
    if (wave < 4)
      *(float4_t*)(out + (size_t)(t + 1) * (BATCH * DATA)
                       + (size_t)(bbase + n) * DATA + wave * 16 + quad * 4) = y;
  }
}

extern "C" void kernel_launch(void* const* d_in, const int* in_sizes, int n_in,
                              void* d_out, int out_size, void* d_ws, size_t ws_size,
                              hipStream_t stream) {
  (void)in_sizes; (void)n_in; (void)out_size; (void)d_ws; (void)ws_size;
  const float* ts = (const float*)d_in[0];
  const float* y0 = (const float*)d_in[1];
  const float* W1 = (const float*)d_in[2];
  const float* b1 = (const float*)d_in[3];
  const float* W2 = (const float*)d_in[4];
  const float* b2 = (const float*)d_in[5];
  const float* W3 = (const float*)d_in[6];
  const float* b3 = (const float*)d_in[7];
  anode_kernel<<<dim3(NWG), dim3(NTHREADS), 0, stream>>>(
      ts, y0, W1, b1, W2, b2, W3, b3, (float*)d_out);
}